// Round 1
// baseline (363.513 us; speedup 1.0000x reference)
//
#include <hip/hip_runtime.h>
#include <hip/hip_bf16.h>

#define B_TOK 8192
#define D_DIM 3072
#define H_DIM 128
#define O_DIM 10
#define N_EXP 8

#define BM 128
#define BK 64
#define HLDS_STRIDE 136   // bf16 elems; row byte stride 272 = 16*17 (keeps ds_read_b128 aligned, staggers banks)

typedef __bf16 bf16x8 __attribute__((ext_vector_type(8)));
typedef float  f32x4  __attribute__((ext_vector_type(4)));

// fp32 -> bf16 round-to-nearest-even
__device__ __forceinline__ unsigned short f2bf(float f) {
  unsigned int u = __float_as_uint(f);
  unsigned int r = (u + 0x7FFFu + ((u >> 16) & 1u)) >> 16;
  return (unsigned short)r;
}

__device__ __forceinline__ void async16(const void* g, void* l) {
  __builtin_amdgcn_global_load_lds(
      (const __attribute__((address_space(1))) void*)g,
      (__attribute__((address_space(3))) void*)l,
      16, 0, 0);
}

// ---------------- K0: W1 [8][3072][128] fp32 -> W1^T [8][128][3072] bf16 ----------------
__global__ void k0_w1_transpose(const float* __restrict__ W1,
                                unsigned short* __restrict__ w1t) {
  __shared__ unsigned short tile[32][33];
  const int e  = blockIdx.z;
  const int d0 = blockIdx.x * 32;
  const int h0 = blockIdx.y * 32;
  const int tx = threadIdx.x;   // 0..31
  const int ty = threadIdx.y;   // 0..7
  const float* src = W1 + ((size_t)e * D_DIM + d0) * H_DIM + h0;
#pragma unroll
  for (int k = 0; k < 4; ++k) {
    int r = ty + 8 * k;
    tile[r][tx] = f2bf(src[(size_t)r * H_DIM + tx]);
  }
  __syncthreads();
  unsigned short* dst = w1t + ((size_t)e * H_DIM + h0) * D_DIM + d0;
#pragma unroll
  for (int k = 0; k < 4; ++k) {
    int r = ty + 8 * k;
    dst[(size_t)r * D_DIM + tx] = tile[tx][r];
  }
}

// ---------------- K1: x -> bf16, gating logits (fp32), top-2 + softmax -> route ----------------
__global__ __launch_bounds__(256) void k1_gate_convert(
    const float* __restrict__ x, const float* __restrict__ Wg,
    const float* __restrict__ bg, unsigned short* __restrict__ xb,
    float4* __restrict__ route) {
  const int b = blockIdx.x;
  const int t = threadIdx.x;
  const float* xrow = x + (size_t)b * D_DIM;
  unsigned short* xbrow = xb + (size_t)b * D_DIM;

  float acc[N_EXP];
#pragma unroll
  for (int n = 0; n < N_EXP; ++n) acc[n] = 0.f;

#pragma unroll
  for (int i = 0; i < 3; ++i) {
    const int d = t * 4 + i * 1024;
    float4 xv = *(const float4*)(xrow + d);
    const float* wgp = Wg + (size_t)d * N_EXP;
#pragma unroll
    for (int j = 0; j < 4; ++j) {
      const float xs = (&xv.x)[j];
#pragma unroll
      for (int n = 0; n < N_EXP; ++n)
        acc[n] = fmaf(xs, wgp[j * N_EXP + n], acc[n]);
    }
    ushort4 pk;
    pk.x = f2bf(xv.x); pk.y = f2bf(xv.y); pk.z = f2bf(xv.z); pk.w = f2bf(xv.w);
    *(ushort4*)(xbrow + d) = pk;
  }

  // reduce 8 accumulators across the wave, then across 4 waves via LDS
#pragma unroll
  for (int n = 0; n < N_EXP; ++n) {
#pragma unroll
    for (int off = 32; off > 0; off >>= 1)
      acc[n] += __shfl_xor(acc[n], off, 64);
  }
  __shared__ float red[4][N_EXP];
  const int lane = t & 63, wv = t >> 6;
  if (lane == 0) {
#pragma unroll
    for (int n = 0; n < N_EXP; ++n) red[wv][n] = acc[n];
  }
  __syncthreads();
  if (t == 0) {
    float g[N_EXP];
#pragma unroll
    for (int n = 0; n < N_EXP; ++n)
      g[n] = red[0][n] + red[1][n] + red[2][n] + red[3][n] + bg[n];
    int i0 = 0;
#pragma unroll
    for (int n = 1; n < N_EXP; ++n) if (g[n] > g[i0]) i0 = n;
    int i1 = (i0 == 0) ? 1 : 0;
#pragma unroll
    for (int n = 0; n < N_EXP; ++n) if (n != i0 && g[n] > g[i1]) i1 = n;
    // softmax over [g[i0], g[i1]], g[i0] >= g[i1]
    float e1 = expf(g[i1] - g[i0]);
    float inv = 1.f / (1.f + e1);
    route[b] = make_float4(inv, e1 * inv, __int_as_float(i0), __int_as_float(i1));
  }
}

// ---------------- K2: per-expert h=relu(x@W1+b1); y=h@W2+b2 -> y_all ----------------
__global__ __launch_bounds__(256) void k2_experts(
    const unsigned short* __restrict__ xb,    // [B][D] bf16
    const unsigned short* __restrict__ w1t,   // [N][H][D] bf16
    const float* __restrict__ b1,             // [N][H]
    const float* __restrict__ W2,             // [N][H][O]
    const float* __restrict__ b2,             // [N][O]
    float* __restrict__ yall) {               // [B][N][O]
  // LDS: loop phase: A tile 128x64 bf16 (16KB) | B tile 128x64 bf16 (16KB)
  //      epilogue:  h tile 128x136 bf16 (34816B, overlays A/B) ; W2^T 16x128 bf16 @34816
  __shared__ __align__(16) unsigned short sm[(34816 + 4096) / 2];
  unsigned short* a_lds   = sm;
  unsigned short* b_lds   = sm + 128 * 64;
  unsigned short* h_lds   = sm;
  unsigned short* w2t_lds = sm + 128 * HLDS_STRIDE;

  const int mblk = blockIdx.x;
  const int e    = blockIdx.y;
  const int tid  = threadIdx.x;
  const int lane = tid & 63;
  const int wv   = tid >> 6;

  // stage W2^T (o-major, k=h contiguous) as bf16; o padded to 16
  const float* W2e = W2 + (size_t)e * H_DIM * O_DIM;
  for (int idx = tid; idx < 16 * 128; idx += 256) {
    int o = idx >> 7, hh = idx & 127;
    float v = (o < O_DIM) ? W2e[hh * O_DIM + o] : 0.f;
    w2t_lds[idx] = f2bf(v);
  }

  const int mhalf = (wv >> 1) * 64;
  const int nhalf = (wv & 1) * 64;

  f32x4 acc[4][4];
#pragma unroll
  for (int i = 0; i < 4; ++i)
#pragma unroll
    for (int j = 0; j < 4; ++j)
      acc[i][j] = (f32x4){0.f, 0.f, 0.f, 0.f};

  const unsigned short* A_base  = xb + (size_t)(mblk * BM) * D_DIM;
  const unsigned short* Bt_base = w1t + (size_t)e * H_DIM * D_DIM;

  const int srow = wv * 32 + (lane >> 3);   // staging row (+ j*8)
  const int scol = (lane & 7) * 8;          // staging k-elem offset

  for (int k0 = 0; k0 < D_DIM; k0 += BK) {
#pragma unroll
    for (int j = 0; j < 4; ++j) {
      const int r = srow + j * 8;
      async16(A_base  + (size_t)r * D_DIM + k0 + scol, a_lds + (wv * 32 + j * 8) * BK);
      async16(Bt_base + (size_t)r * D_DIM + k0 + scol, b_lds + (wv * 32 + j * 8) * BK);
    }
    __syncthreads();
#pragma unroll
    for (int kk = 0; kk < 2; ++kk) {
      bf16x8 af[4], bfr[4];
      const int krd = kk * 32 + (lane >> 4) * 8;
#pragma unroll
      for (int mi = 0; mi < 4; ++mi)
        af[mi] = *(const bf16x8*)(a_lds + (mhalf + mi * 16 + (lane & 15)) * BK + krd);
#pragma unroll
      for (int ni = 0; ni < 4; ++ni)
        bfr[ni] = *(const bf16x8*)(b_lds + (nhalf + ni * 16 + (lane & 15)) * BK + krd);
#pragma unroll
      for (int mi = 0; mi < 4; ++mi)
#pragma unroll
        for (int ni = 0; ni < 4; ++ni)
          acc[mi][ni] = __builtin_amdgcn_mfma_f32_16x16x32_bf16(af[mi], bfr[ni], acc[mi][ni], 0, 0, 0);
    }
    __syncthreads();
  }

  // epilogue 1: h = relu(acc + b1) -> h_lds (bf16). C/D layout: col=lane&15, row=quad*4+r
  const float* b1e = b1 + e * H_DIM;
#pragma unroll
  for (int ni = 0; ni < 4; ++ni) {
    const int col  = nhalf + ni * 16 + (lane & 15);
    const float bias = b1e[col];
#pragma unroll
    for (int mi = 0; mi < 4; ++mi) {
      const int rbase = mhalf + mi * 16 + ((lane >> 4) << 2);
#pragma unroll
      for (int r = 0; r < 4; ++r) {
        float v = acc[mi][ni][r] + bias;
        v = v > 0.f ? v : 0.f;
        h_lds[(rbase + r) * HLDS_STRIDE + col] = f2bf(v);
      }
    }
  }
  __syncthreads();

  // epilogue 2: y[128x16] = h[128x128] @ W2[128x16]; wave handles 32 token rows
  f32x4 acc2[2];
  acc2[0] = (f32x4){0.f, 0.f, 0.f, 0.f};
  acc2[1] = (f32x4){0.f, 0.f, 0.f, 0.f};
#pragma unroll
  for (int ks = 0; ks < 4; ++ks) {
    const int krd = ks * 32 + (lane >> 4) * 8;
    bf16x8 bfr = *(const bf16x8*)(w2t_lds + (lane & 15) * 128 + krd);
#pragma unroll
    for (int mi = 0; mi < 2; ++mi) {
      bf16x8 afr = *(const bf16x8*)(h_lds + (wv * 32 + mi * 16 + (lane & 15)) * HLDS_STRIDE + krd);
      acc2[mi] = __builtin_amdgcn_mfma_f32_16x16x32_bf16(afr, bfr, acc2[mi], 0, 0, 0);
    }
  }
  const int o = lane & 15;
  if (o < O_DIM) {
    const float bias2 = b2[e * O_DIM + o];
#pragma unroll
    for (int mi = 0; mi < 2; ++mi) {
#pragma unroll
      for (int r = 0; r < 4; ++r) {
        const int row = mblk * BM + wv * 32 + mi * 16 + ((lane >> 4) << 2) + r;
        yall[((size_t)row * N_EXP + e) * O_DIM + o] = acc2[mi][r] + bias2;
      }
    }
  }
}

// ---------------- K3: combine top-2 ----------------
__global__ __launch_bounds__(256) void k3_combine(
    const float* __restrict__ yall, const float4* __restrict__ route,
    float* __restrict__ out) {
  const int g = blockIdx.x * 256 + threadIdx.x;
  if (g >= B_TOK * O_DIM) return;
  const int b = g / O_DIM, o = g - b * O_DIM;
  const float4 r = route[b];
  const int i0 = __float_as_int(r.z), i1 = __float_as_int(r.w);
  out[g] = r.x * yall[((size_t)b * N_EXP + i0) * O_DIM + o] +
           r.y * yall[((size_t)b * N_EXP + i1) * O_DIM + o];
}

extern "C" void kernel_launch(void* const* d_in, const int* in_sizes, int n_in,
                              void* d_out, int out_size, void* d_ws, size_t ws_size,
                              hipStream_t stream) {
  const float* x  = (const float*)d_in[0];
  const float* Wg = (const float*)d_in[1];
  const float* bg = (const float*)d_in[2];
  const float* W1 = (const float*)d_in[3];
  const float* b1 = (const float*)d_in[4];
  const float* W2 = (const float*)d_in[5];
  const float* b2 = (const float*)d_in[6];
  float* out = (float*)d_out;

  char* ws = (char*)d_ws;
  // ws layout (bytes): xb 50331648 | w1t 6291456 | route 131072 | yall 2621440  (~59.4 MB)
  unsigned short* xb  = (unsigned short*)ws;
  unsigned short* w1t = (unsigned short*)(ws + 50331648);
  float4* route       = (float4*)(ws + 56623104);
  float* yall         = (float*)(ws + 56754176);

  k0_w1_transpose<<<dim3(96, 4, 8), dim3(32, 8), 0, stream>>>(W1, w1t);
  k1_gate_convert<<<dim3(B_TOK), dim3(256), 0, stream>>>(x, Wg, bg, xb, route);
  k2_experts<<<dim3(B_TOK / BM, N_EXP), dim3(256), 0, stream>>>(xb, w1t, b1, W2, b2, yall);
  k3_combine<<<dim3((B_TOK * O_DIM + 255) / 256), dim3(256), 0, stream>>>(yall, route, out);
}

// Round 2
// 263.581 us; speedup vs baseline: 1.3791x; 1.3791x over previous
//
#include <hip/hip_runtime.h>
#include <hip/hip_bf16.h>

#define B_TOK 8192
#define D_DIM 3072
#define H_DIM 128
#define O_DIM 10
#define N_EXP 8

#define BM 128
#define BK 64
#define HLDS_STRIDE 136   // bf16 elems; row byte stride 272 = 16*17 (keeps ds_read_b128 aligned, staggers banks)

typedef __bf16 bf16x8 __attribute__((ext_vector_type(8)));
typedef float  f32x4  __attribute__((ext_vector_type(4)));

// fp32 -> bf16 round-to-nearest-even
__device__ __forceinline__ unsigned short f2bf(float f) {
  unsigned int u = __float_as_uint(f);
  unsigned int r = (u + 0x7FFFu + ((u >> 16) & 1u)) >> 16;
  return (unsigned short)r;
}

__device__ __forceinline__ void async16(const void* g, void* l) {
  __builtin_amdgcn_global_load_lds(
      (const __attribute__((address_space(1))) void*)g,
      (__attribute__((address_space(3))) void*)l,
      16, 0, 0);
}

// ---------------- K0: W1 [8][3072][128] fp32 -> W1^T [8][128][3072] bf16 ----------------
__global__ void k0_w1_transpose(const float* __restrict__ W1,
                                unsigned short* __restrict__ w1t) {
  __shared__ unsigned short tile[32][33];
  const int e  = blockIdx.z;
  const int d0 = blockIdx.x * 32;
  const int h0 = blockIdx.y * 32;
  const int tx = threadIdx.x;   // 0..31
  const int ty = threadIdx.y;   // 0..7
  const float* src = W1 + ((size_t)e * D_DIM + d0) * H_DIM + h0;
#pragma unroll
  for (int k = 0; k < 4; ++k) {
    int r = ty + 8 * k;
    tile[r][tx] = f2bf(src[(size_t)r * H_DIM + tx]);
  }
  __syncthreads();
  unsigned short* dst = w1t + ((size_t)e * H_DIM + h0) * D_DIM + d0;
#pragma unroll
  for (int k = 0; k < 4; ++k) {
    int r = ty + 8 * k;
    dst[(size_t)r * D_DIM + tx] = tile[tx][r];
  }
}

// ---------------- K1: x -> bf16, gating logits (fp32), top-2 + softmax -> route ----------------
// One wave per token; lanes stride D. Wg staged in LDS as [n][d] so bank = d%32
// (2-way aliasing across the 64 lanes = free). x reads are 256B-contiguous scalar
// loads; xb writes 128B-contiguous. Gating math stays fp32 (top-2 tie safety).
__global__ __launch_bounds__(256) void k1_gate_convert(
    const float* __restrict__ x, const float* __restrict__ Wg,
    const float* __restrict__ bg, unsigned short* __restrict__ xb,
    float4* __restrict__ route) {
  __shared__ float wg_lds[N_EXP * D_DIM];  // 96 KB, [n][d]
  const int tid = threadIdx.x;

  // stage Wg [D][N] row-major -> lds [n][d], float4 global reads
  for (int f = tid; f < D_DIM * N_EXP / 4; f += 256) {
    const float4 v = ((const float4*)Wg)[f];
    const int d  = f >> 1;
    const int nh = (f & 1) * 4;
    wg_lds[(nh + 0) * D_DIM + d] = v.x;
    wg_lds[(nh + 1) * D_DIM + d] = v.y;
    wg_lds[(nh + 2) * D_DIM + d] = v.z;
    wg_lds[(nh + 3) * D_DIM + d] = v.w;
  }
  __syncthreads();

  const int lane = tid & 63;
  const int wv   = tid >> 6;

  for (int ti = 0; ti < 8; ++ti) {
    const int tk = blockIdx.x * 32 + ti * 4 + wv;
    const float* xr = x + (size_t)tk * D_DIM;
    unsigned short* xbr = xb + (size_t)tk * D_DIM;

    float acc[N_EXP];
#pragma unroll
    for (int n = 0; n < N_EXP; ++n) acc[n] = 0.f;

#pragma unroll 12
    for (int jj = 0; jj < D_DIM / 64; ++jj) {
      const int d = jj * 64 + lane;
      const float xs = xr[d];
      xbr[d] = f2bf(xs);
#pragma unroll
      for (int n = 0; n < N_EXP; ++n)
        acc[n] = fmaf(xs, wg_lds[n * D_DIM + d], acc[n]);
    }

#pragma unroll
    for (int n = 0; n < N_EXP; ++n) {
#pragma unroll
      for (int off = 32; off > 0; off >>= 1)
        acc[n] += __shfl_xor(acc[n], off, 64);
    }
    if (lane == 0) {
      float g[N_EXP];
#pragma unroll
      for (int n = 0; n < N_EXP; ++n) g[n] = acc[n] + bg[n];
      int i0 = 0;
#pragma unroll
      for (int n = 1; n < N_EXP; ++n) if (g[n] > g[i0]) i0 = n;
      int i1 = (i0 == 0) ? 1 : 0;
#pragma unroll
      for (int n = 0; n < N_EXP; ++n) if (n != i0 && g[n] > g[i1]) i1 = n;
      float e1 = expf(g[i1] - g[i0]);
      float inv = 1.f / (1.f + e1);
      route[tk] = make_float4(inv, e1 * inv, __int_as_float(i0), __int_as_float(i1));
    }
  }
}

// ---------------- K2: per-expert h=relu(x@W1+b1); y=h@W2+b2 -> y_all ----------------
__global__ __launch_bounds__(256) void k2_experts(
    const unsigned short* __restrict__ xb,    // [B][D] bf16
    const unsigned short* __restrict__ w1t,   // [N][H][D] bf16
    const float* __restrict__ b1,             // [N][H]
    const float* __restrict__ W2,             // [N][H][O]
    const float* __restrict__ b2,             // [N][O]
    float* __restrict__ yall) {               // [B][N][O]
  // LDS: loop phase: A tile 128x64 bf16 (16KB) | B tile 128x64 bf16 (16KB)
  //      epilogue:  h tile 128x136 bf16 (34816B, overlays A/B) ; W2^T 16x128 bf16 @34816
  __shared__ __align__(16) unsigned short sm[(34816 + 4096) / 2];
  unsigned short* a_lds   = sm;
  unsigned short* b_lds   = sm + 128 * 64;
  unsigned short* h_lds   = sm;
  unsigned short* w2t_lds = sm + 128 * HLDS_STRIDE;

  const int mblk = blockIdx.x;
  const int e    = blockIdx.y;
  const int tid  = threadIdx.x;
  const int lane = tid & 63;
  const int wv   = tid >> 6;

  // stage W2^T (o-major, k=h contiguous) as bf16; o padded to 16
  const float* W2e = W2 + (size_t)e * H_DIM * O_DIM;
  for (int idx = tid; idx < 16 * 128; idx += 256) {
    int o = idx >> 7, hh = idx & 127;
    float v = (o < O_DIM) ? W2e[hh * O_DIM + o] : 0.f;
    w2t_lds[idx] = f2bf(v);
  }

  const int mhalf = (wv >> 1) * 64;
  const int nhalf = (wv & 1) * 64;

  f32x4 acc[4][4];
#pragma unroll
  for (int i = 0; i < 4; ++i)
#pragma unroll
    for (int j = 0; j < 4; ++j)
      acc[i][j] = (f32x4){0.f, 0.f, 0.f, 0.f};

  const unsigned short* A_base  = xb + (size_t)(mblk * BM) * D_DIM;
  const unsigned short* Bt_base = w1t + (size_t)e * H_DIM * D_DIM;

  const int srow = wv * 32 + (lane >> 3);   // staging row (+ j*8)
  const int scol = (lane & 7) * 8;          // staging k-elem offset

  for (int k0 = 0; k0 < D_DIM; k0 += BK) {
#pragma unroll
    for (int j = 0; j < 4; ++j) {
      const int r = srow + j * 8;
      async16(A_base  + (size_t)r * D_DIM + k0 + scol, a_lds + (wv * 32 + j * 8) * BK);
      async16(Bt_base + (size_t)r * D_DIM + k0 + scol, b_lds + (wv * 32 + j * 8) * BK);
    }
    __syncthreads();
#pragma unroll
    for (int kk = 0; kk < 2; ++kk) {
      bf16x8 af[4], bfr[4];
      const int krd = kk * 32 + (lane >> 4) * 8;
#pragma unroll
      for (int mi = 0; mi < 4; ++mi)
        af[mi] = *(const bf16x8*)(a_lds + (mhalf + mi * 16 + (lane & 15)) * BK + krd);
#pragma unroll
      for (int ni = 0; ni < 4; ++ni)
        bfr[ni] = *(const bf16x8*)(b_lds + (nhalf + ni * 16 + (lane & 15)) * BK + krd);
#pragma unroll
      for (int mi = 0; mi < 4; ++mi)
#pragma unroll
        for (int ni = 0; ni < 4; ++ni)
          acc[mi][ni] = __builtin_amdgcn_mfma_f32_16x16x32_bf16(af[mi], bfr[ni], acc[mi][ni], 0, 0, 0);
    }
    __syncthreads();
  }

  // epilogue 1: h = relu(acc + b1) -> h_lds (bf16). C/D layout: col=lane&15, row=quad*4+r
  const float* b1e = b1 + e * H_DIM;
#pragma unroll
  for (int ni = 0; ni < 4; ++ni) {
    const int col  = nhalf + ni * 16 + (lane & 15);
    const float bias = b1e[col];
#pragma unroll
    for (int mi = 0; mi < 4; ++mi) {
      const int rbase = mhalf + mi * 16 + ((lane >> 4) << 2);
#pragma unroll
      for (int r = 0; r < 4; ++r) {
        float v = acc[mi][ni][r] + bias;
        v = v > 0.f ? v : 0.f;
        h_lds[(rbase + r) * HLDS_STRIDE + col] = f2bf(v);
      }
    }
  }
  __syncthreads();

  // epilogue 2: y[128x16] = h[128x128] @ W2[128x16]; wave handles 32 token rows
  f32x4 acc2[2];
  acc2[0] = (f32x4){0.f, 0.f, 0.f, 0.f};
  acc2[1] = (f32x4){0.f, 0.f, 0.f, 0.f};
#pragma unroll
  for (int ks = 0; ks < 4; ++ks) {
    const int krd = ks * 32 + (lane >> 4) * 8;
    bf16x8 bfr = *(const bf16x8*)(w2t_lds + (lane & 15) * 128 + krd);
#pragma unroll
    for (int mi = 0; mi < 2; ++mi) {
      bf16x8 afr = *(const bf16x8*)(h_lds + (wv * 32 + mi * 16 + (lane & 15)) * HLDS_STRIDE + krd);
      acc2[mi] = __builtin_amdgcn_mfma_f32_16x16x32_bf16(afr, bfr, acc2[mi], 0, 0, 0);
    }
  }
  const int o = lane & 15;
  if (o < O_DIM) {
    const float bias2 = b2[e * O_DIM + o];
#pragma unroll
    for (int mi = 0; mi < 2; ++mi) {
#pragma unroll
      for (int r = 0; r < 4; ++r) {
        const int row = mblk * BM + wv * 32 + mi * 16 + ((lane >> 4) << 2) + r;
        yall[((size_t)row * N_EXP + e) * O_DIM + o] = acc2[mi][r] + bias2;
      }
    }
  }
}

// ---------------- K3: combine top-2 ----------------
__global__ __launch_bounds__(256) void k3_combine(
    const float* __restrict__ yall, const float4* __restrict__ route,
    float* __restrict__ out) {
  const int g = blockIdx.x * 256 + threadIdx.x;
  if (g >= B_TOK * O_DIM) return;
  const int b = g / O_DIM, o = g - b * O_DIM;
  const float4 r = route[b];
  const int i0 = __float_as_int(r.z), i1 = __float_as_int(r.w);
  out[g] = r.x * yall[((size_t)b * N_EXP + i0) * O_DIM + o] +
           r.y * yall[((size_t)b * N_EXP + i1) * O_DIM + o];
}

extern "C" void kernel_launch(void* const* d_in, const int* in_sizes, int n_in,
                              void* d_out, int out_size, void* d_ws, size_t ws_size,
                              hipStream_t stream) {
  const float* x  = (const float*)d_in[0];
  const float* Wg = (const float*)d_in[1];
  const float* bg = (const float*)d_in[2];
  const float* W1 = (const float*)d_in[3];
  const float* b1 = (const float*)d_in[4];
  const float* W2 = (const float*)d_in[5];
  const float* b2 = (const float*)d_in[6];
  float* out = (float*)d_out;

  char* ws = (char*)d_ws;
  // ws layout (bytes): xb 50331648 | w1t 6291456 | route 131072 | yall 2621440  (~59.4 MB)
  unsigned short* xb  = (unsigned short*)ws;
  unsigned short* w1t = (unsigned short*)(ws + 50331648);
  float4* route       = (float4*)(ws + 56623104);
  float* yall         = (float*)(ws + 56754176);

  k0_w1_transpose<<<dim3(96, 4, 8), dim3(32, 8), 0, stream>>>(W1, w1t);
  k1_gate_convert<<<dim3(B_TOK / 32), dim3(256), 0, stream>>>(x, Wg, bg, xb, route);
  k2_experts<<<dim3(B_TOK / BM, N_EXP), dim3(256), 0, stream>>>(xb, w1t, b1, W2, b2, yall);
  k3_combine<<<dim3((B_TOK * O_DIM + 255) / 256), dim3(256), 0, stream>>>(yall, route, out);
}